// Round 1
// baseline (725.727 us; speedup 1.0000x reference)
//
#include <hip/hip_runtime.h>
#include <hip/hip_bf16.h>
#include <stdint.h>

typedef __bf16 bf16_t;
typedef __bf16 bf16x8 __attribute__((ext_vector_type(8)));
typedef __bf16 bf16x4 __attribute__((ext_vector_type(4)));
typedef float f32x4 __attribute__((ext_vector_type(4)));

#define NPIX 4096
#define CH 256

// ---------------- GroupNorm stats (2-stage) ----------------
// grid (64*8): blockIdx = bg*8 + chunk ; partial sums atomically accumulated
__global__ __launch_bounds__(256) void gn_partial_k(const float* __restrict__ x,
                                                    float* __restrict__ acc2) {
  int bg = blockIdx.x >> 3;
  int chunk = blockIdx.x & 7;
  const float4* xp = (const float4*)(x + (size_t)bg * 32 * NPIX) + chunk * (32 * NPIX / 4 / 8);
  float s = 0.f, ss = 0.f;
  for (int i = threadIdx.x; i < 32 * NPIX / 4 / 8; i += 256) {
    float4 v = xp[i];
    s  += v.x + v.y + v.z + v.w;
    ss += v.x * v.x + v.y * v.y + v.z * v.z + v.w * v.w;
  }
  int l = threadIdx.x & 63, w = threadIdx.x >> 6;
  #pragma unroll
  for (int off = 32; off; off >>= 1) { s += __shfl_down(s, off); ss += __shfl_down(ss, off); }
  __shared__ float rs[4], rss[4];
  if (l == 0) { rs[w] = s; rss[w] = ss; }
  __syncthreads();
  if (threadIdx.x == 0) {
    atomicAdd(&acc2[bg * 2],     rs[0] + rs[1] + rs[2] + rs[3]);
    atomicAdd(&acc2[bg * 2 + 1], rss[0] + rss[1] + rss[2] + rss[3]);
  }
}

__global__ void gn_finalize_k(const float* __restrict__ acc2, float* __restrict__ stats) {
  int bg = threadIdx.x;  // 64 threads
  float mean = acc2[bg * 2] * (1.f / (32.f * NPIX));
  float var  = acc2[bg * 2 + 1] * (1.f / (32.f * NPIX)) - mean * mean;
  stats[bg * 2]     = mean;
  stats[bg * 2 + 1] = rsqrtf(var + 1e-5f);
}

// ------------- normalize + transpose [b][c][p] -> bf16 [b][p][c] -------------
__global__ __launch_bounds__(256) void gn_apply_t_k(const float* __restrict__ x,
    const float* __restrict__ stats, const float* __restrict__ gamma,
    const float* __restrict__ beta, bf16_t* __restrict__ xnT) {
  __shared__ float tile[32][33];
  int b = blockIdx.z;
  int p0 = blockIdx.x * 32, c0 = blockIdx.y * 32;
  int g = c0 >> 5;
  float mean = stats[(b * 8 + g) * 2], rstd = stats[(b * 8 + g) * 2 + 1];
  int tx = threadIdx.x, ty = threadIdx.y;
  const float* xb = x + ((size_t)b * CH + c0) * NPIX + p0;
  #pragma unroll
  for (int j = 0; j < 4; ++j) {
    int c = ty + j * 8;
    float v = xb[(size_t)c * NPIX + tx];
    tile[c][tx] = (v - mean) * rstd * gamma[c0 + c] + beta[c0 + c];
  }
  __syncthreads();
  bf16_t* op = xnT + ((size_t)b * NPIX + p0) * CH + c0;
  #pragma unroll
  for (int j = 0; j < 4; ++j) {
    int p = ty + j * 8;
    op[(size_t)p * CH + tx] = (bf16_t)tile[tx][p];
  }
}

// ---------------- cast weights to bf16 ----------------
__global__ __launch_bounds__(256) void cast_w_k(const float* __restrict__ wq,
    const float* __restrict__ wp, bf16_t* __restrict__ wqb, bf16_t* __restrict__ wpb) {
  int i = blockIdx.x * 256 + threadIdx.x;
  if (i < 768 * 256) wqb[i] = (bf16_t)wq[i];
  if (i < 256 * 256) wpb[i] = (bf16_t)wp[i];
}

// ---------------- row softmax, in place: f32 row -> bf16 row (front half) ----------------
__global__ __launch_bounds__(256) void softmax_k(float* __restrict__ S) {
  int row = blockIdx.x;
  float* sp = S + (size_t)row * NPIX;
  int t = threadIdx.x;
  float4 vals[4];
  float m = -1e30f;
  #pragma unroll
  for (int j = 0; j < 4; ++j) {
    vals[j] = ((const float4*)sp)[t + j * 256];
    m = fmaxf(m, fmaxf(fmaxf(vals[j].x, vals[j].y), fmaxf(vals[j].z, vals[j].w)));
  }
  int l = t & 63, w = t >> 6;
  #pragma unroll
  for (int off = 32; off; off >>= 1) m = fmaxf(m, __shfl_down(m, off));
  __shared__ float rm[4], rsum[4];
  if (!l) rm[w] = m;
  __syncthreads();
  m = fmaxf(fmaxf(rm[0], rm[1]), fmaxf(rm[2], rm[3]));
  float s = 0.f;
  #pragma unroll
  for (int j = 0; j < 4; ++j) {
    vals[j].x = __expf(vals[j].x - m); vals[j].y = __expf(vals[j].y - m);
    vals[j].z = __expf(vals[j].z - m); vals[j].w = __expf(vals[j].w - m);
    s += vals[j].x + vals[j].y + vals[j].z + vals[j].w;
  }
  #pragma unroll
  for (int off = 32; off; off >>= 1) s += __shfl_down(s, off);
  if (!l) rsum[w] = s;
  __syncthreads();  // also guarantees all loads done before in-place stores
  float inv = 1.f / (rsum[0] + rsum[1] + rsum[2] + rsum[3]);
  bf16x4* pp = (bf16x4*)sp;
  #pragma unroll
  for (int j = 0; j < 4; ++j) {
    bf16x4 o;
    o[0] = (bf16_t)(vals[j].x * inv); o[1] = (bf16_t)(vals[j].y * inv);
    o[2] = (bf16_t)(vals[j].z * inv); o[3] = (bf16_t)(vals[j].w * inv);
    pp[t + j * 256] = o;
  }
}

// ---------------- reduce 4 split-K slices + cast to bf16 ----------------
__global__ __launch_bounds__(256) void reduce_ot_k(const float4* __restrict__ src,
                                                   bf16x4* __restrict__ dst) {
  int i = blockIdx.x * 256 + threadIdx.x;  // < NPIX*CH/4 = 262144
  float4 a = src[i];
  float4 b = src[i + 262144];
  float4 c = src[i + 2 * 262144];
  float4 d = src[i + 3 * 262144];
  bf16x4 o;
  o[0] = (bf16_t)(a.x + b.x + c.x + d.x);
  o[1] = (bf16_t)(a.y + b.y + c.y + d.y);
  o[2] = (bf16_t)(a.z + b.z + c.z + d.z);
  o[3] = (bf16_t)(a.w + b.w + c.w + d.w);
  dst[i] = o;
}

// ---------------- NT GEMM: C[M][N] = sum_k A[m][k] * B[n][k] ----------------
// 128x128 tile, BK=32, 4 waves (2x2), mfma_f32_16x16x32_bf16, reg-staged LDS.
// MODE 0: QKV   (z=batch) out: q,k -> qkT[p][512] bf16 (+bias); v -> v[c][n] bf16 (+bias)
// MODE 1: QK^T  out: S fp32 * 1/16
// MODE 2: PV    (z=splitK/4) out: fp32 slice [z][p][c]
// MODE 3: proj  (z=batch) out: fp32 d_out = acc + b_proj[o] + x
#define LSTR 80  // LDS row stride bytes: 64 data + 16 pad (kills 8-way ds_read conflict)

template <int MODE>
__global__ __launch_bounds__(256) void gemm_nt_k(
    const bf16_t* __restrict__ Ag, const bf16_t* __restrict__ Bg,
    int lda, int ldb, int K,
    void* __restrict__ O0, void* __restrict__ O1,
    const float* __restrict__ bias, const float* __restrict__ resid) {
  __shared__ __align__(16) char ldsA[128 * LSTR];
  __shared__ __align__(16) char ldsB[128 * LSTR];

  const int t = threadIdx.x;
  const int l = t & 63;
  const int w = t >> 6;
  const int wr = w >> 1, wc = w & 1;
  const int bm = blockIdx.x * 128;
  const int bn = blockIdx.y * 128;
  const int bz = blockIdx.z;

  const bf16_t* Ap = Ag;
  const bf16_t* Bp = Bg;
  if constexpr (MODE == 0) Ap += (size_t)bz * NPIX * CH;
  if constexpr (MODE == 3) Bp += (size_t)bz * NPIX * CH;
  int k_begin = 0, k_end = K;
  if constexpr (MODE == 2) { k_begin = bz * (K >> 2); k_end = k_begin + (K >> 2); }

  f32x4 acc[4][4] = {};

  const int srow = t >> 2;         // 0..63
  const int scol = (t & 3) * 8;    // bf16 elem offset within 32-wide k tile

  for (int k0 = k_begin; k0 < k_end; k0 += 32) {
    __syncthreads();
    #pragma unroll
    for (int it = 0; it < 2; ++it) {
      int r = it * 64 + srow;
      *(bf16x8*)(ldsA + r * LSTR + scol * 2) =
          *(const bf16x8*)(Ap + (size_t)(bm + r) * lda + k0 + scol);
      *(bf16x8*)(ldsB + r * LSTR + scol * 2) =
          *(const bf16x8*)(Bp + (size_t)(bn + r) * ldb + k0 + scol);
    }
    __syncthreads();
    bf16x8 fa[4], fb[4];
    #pragma unroll
    for (int m = 0; m < 4; ++m)
      fa[m] = *(const bf16x8*)(ldsA + (wr * 64 + m * 16 + (l & 15)) * LSTR + (l >> 4) * 16);
    #pragma unroll
    for (int n = 0; n < 4; ++n)
      fb[n] = *(const bf16x8*)(ldsB + (wc * 64 + n * 16 + (l & 15)) * LSTR + (l >> 4) * 16);
    #pragma unroll
    for (int m = 0; m < 4; ++m)
      #pragma unroll
      for (int n = 0; n < 4; ++n)
        acc[m][n] = __builtin_amdgcn_mfma_f32_16x16x32_bf16(fa[m], fb[n], acc[m][n], 0, 0, 0);
  }

  // C/D layout: col = lane&15, row = (lane>>4)*4 + reg  [m89-verified]
  const int r0 = bm + wr * 64 + (l >> 4) * 4;
  const int c0 = bn + wc * 64 + (l & 15);
  #pragma unroll
  for (int m = 0; m < 4; ++m) {
    #pragma unroll
    for (int n = 0; n < 4; ++n) {
      int col = c0 + n * 16;
      #pragma unroll
      for (int j = 0; j < 4; ++j) {
        int row = r0 + m * 16 + j;
        float v = acc[m][n][j];
        if constexpr (MODE == 0) {
          float val = v + bias[col];
          if (col < 512)
            ((bf16_t*)O0)[(size_t)bz * NPIX * 512 + (size_t)row * 512 + col] = (bf16_t)val;
          else
            ((bf16_t*)O1)[(size_t)bz * CH * NPIX + (size_t)(col - 512) * NPIX + row] = (bf16_t)val;
        } else if constexpr (MODE == 1) {
          ((float*)O0)[(size_t)row * NPIX + col] = v * 0.0625f;
        } else if constexpr (MODE == 2) {
          ((float*)O0)[(size_t)bz * NPIX * CH + (size_t)row * CH + col] = v;
        } else {
          size_t idx = (size_t)bz * CH * NPIX + (size_t)row * NPIX + col;
          ((float*)O0)[idx] = v + bias[row] + resid[idx];
        }
      }
    }
  }
}

extern "C" void kernel_launch(void* const* d_in, const int* in_sizes, int n_in,
                              void* d_out, int out_size, void* d_ws, size_t ws_size,
                              hipStream_t stream) {
  const float* x      = (const float*)d_in[0];
  const float* gamma  = (const float*)d_in[1];
  const float* beta   = (const float*)d_in[2];
  const float* w_qkv  = (const float*)d_in[3];
  const float* b_qkv  = (const float*)d_in[4];
  const float* w_proj = (const float*)d_in[5];
  const float* b_proj = (const float*)d_in[6];

  char* p = (char*)d_ws;
  auto alloc = [&](size_t bytes) {
    char* r = p;
    p += (bytes + 255) & ~(size_t)255;
    return (void*)r;
  };
  bf16_t* qkT  = (bf16_t*)alloc((size_t)8 * NPIX * 512 * 2);  // 32MB  [b][p][0:512] q|k
  bf16_t* vbuf = (bf16_t*)alloc((size_t)8 * CH * NPIX * 2);   // 16MB  [b][c][p]
  bf16_t* OT   = (bf16_t*)alloc((size_t)8 * NPIX * CH * 2);   // 16MB  [b][p][c]
  float*  Sbuf = (float*)alloc((size_t)NPIX * NPIX * 4);      // 64MB  one batch (P bf16 in place)
  float*  OTf  = (float*)alloc((size_t)4 * NPIX * CH * 4);    // 16MB  4 split-K slices
  bf16_t* wqb  = (bf16_t*)alloc(768 * 256 * 2);
  bf16_t* wpb  = (bf16_t*)alloc(256 * 256 * 2);
  float*  acc2 = (float*)alloc(64 * 2 * 4);
  float*  stats= (float*)alloc(64 * 2 * 4);
  bf16_t* xnT  = (bf16_t*)d_out;  // scratch: dead before final proj writes d_out

  hipMemsetAsync(acc2, 0, 64 * 2 * 4, stream);
  gn_partial_k<<<64 * 8, 256, 0, stream>>>(x, acc2);
  gn_finalize_k<<<1, 64, 0, stream>>>(acc2, stats);
  gn_apply_t_k<<<dim3(128, 8, 8), dim3(32, 8), 0, stream>>>(x, stats, gamma, beta, xnT);
  cast_w_k<<<768, 256, 0, stream>>>(w_qkv, w_proj, wqb, wpb);

  // QKV: [p][o] = xnT[p][c] . w_qkv[o][c]   (all batches)
  gemm_nt_k<0><<<dim3(32, 6, 8), 256, 0, stream>>>(xnT, wqb, CH, CH, CH,
                                                   qkT, vbuf, b_qkv, nullptr);
  for (int b = 0; b < 8; ++b) {
    bf16_t* qk_b = qkT + (size_t)b * NPIX * 512;
    bf16_t* v_b  = vbuf + (size_t)b * CH * NPIX;
    // scores: S[i][j] = q[i].k[j] / 16
    gemm_nt_k<1><<<dim3(32, 32, 1), 256, 0, stream>>>(qk_b, qk_b + 256, 512, 512, CH,
                                                      Sbuf, nullptr, nullptr, nullptr);
    softmax_k<<<NPIX, 256, 0, stream>>>(Sbuf);
    // PV: OT[i][c] = sum_j P[i][j] v[c][j]  (P bf16 rows at stride 8192 elems, split-K=4)
    gemm_nt_k<2><<<dim3(32, 2, 4), 256, 0, stream>>>((bf16_t*)Sbuf, v_b, 8192, NPIX, NPIX,
                                                     OTf, nullptr, nullptr, nullptr);
    reduce_ot_k<<<NPIX * CH / 4 / 256, 256, 0, stream>>>((const float4*)OTf,
                                                         (bf16x4*)(OT + (size_t)b * NPIX * CH));
  }
  // proj + bias + residual: out[b][o][p] = x + w_proj[o][c] . OT[p][c] + b_proj[o]
  gemm_nt_k<3><<<dim3(2, 32, 8), 256, 0, stream>>>(wpb, OT, CH, CH, CH,
                                                   d_out, nullptr, b_proj, x);
}

// Round 2
// 447.145 us; speedup vs baseline: 1.6230x; 1.6230x over previous
//
#include <hip/hip_runtime.h>
#include <hip/hip_bf16.h>
#include <stdint.h>

typedef __bf16 bf16_t;
typedef __bf16 bf16x8 __attribute__((ext_vector_type(8)));
typedef __bf16 bf16x4 __attribute__((ext_vector_type(4)));
typedef float f32x4 __attribute__((ext_vector_type(4)));
typedef float f32x16 __attribute__((ext_vector_type(16)));

#define NPIX 4096
#define CH 256

// ---------------- GroupNorm stats (2-stage) ----------------
__global__ __launch_bounds__(256) void gn_partial_k(const float* __restrict__ x,
                                                    float* __restrict__ acc2) {
  int bg = blockIdx.x >> 3;
  int chunk = blockIdx.x & 7;
  const float4* xp = (const float4*)(x + (size_t)bg * 32 * NPIX) + chunk * (32 * NPIX / 4 / 8);
  float s = 0.f, ss = 0.f;
  for (int i = threadIdx.x; i < 32 * NPIX / 4 / 8; i += 256) {
    float4 v = xp[i];
    s  += v.x + v.y + v.z + v.w;
    ss += v.x * v.x + v.y * v.y + v.z * v.z + v.w * v.w;
  }
  int l = threadIdx.x & 63, w = threadIdx.x >> 6;
  #pragma unroll
  for (int off = 32; off; off >>= 1) { s += __shfl_down(s, off); ss += __shfl_down(ss, off); }
  __shared__ float rs[4], rss[4];
  if (l == 0) { rs[w] = s; rss[w] = ss; }
  __syncthreads();
  if (threadIdx.x == 0) {
    atomicAdd(&acc2[bg * 2],     rs[0] + rs[1] + rs[2] + rs[3]);
    atomicAdd(&acc2[bg * 2 + 1], rss[0] + rss[1] + rss[2] + rss[3]);
  }
}

__global__ void gn_finalize_k(const float* __restrict__ acc2, float* __restrict__ stats) {
  int bg = threadIdx.x;  // 64 threads
  float mean = acc2[bg * 2] * (1.f / (32.f * NPIX));
  float var  = acc2[bg * 2 + 1] * (1.f / (32.f * NPIX)) - mean * mean;
  stats[bg * 2]     = mean;
  stats[bg * 2 + 1] = rsqrtf(var + 1e-5f);
}

// ------------- normalize + transpose [b][c][p] -> bf16 [b][p][c] -------------
__global__ __launch_bounds__(256) void gn_apply_t_k(const float* __restrict__ x,
    const float* __restrict__ stats, const float* __restrict__ gamma,
    const float* __restrict__ beta, bf16_t* __restrict__ xnT) {
  __shared__ float tile[32][33];
  int b = blockIdx.z;
  int p0 = blockIdx.x * 32, c0 = blockIdx.y * 32;
  int g = c0 >> 5;
  float mean = stats[(b * 8 + g) * 2], rstd = stats[(b * 8 + g) * 2 + 1];
  int tx = threadIdx.x, ty = threadIdx.y;
  const float* xb = x + ((size_t)b * CH + c0) * NPIX + p0;
  #pragma unroll
  for (int j = 0; j < 4; ++j) {
    int c = ty + j * 8;
    float v = xb[(size_t)c * NPIX + tx];
    tile[c][tx] = (v - mean) * rstd * gamma[c0 + c] + beta[c0 + c];
  }
  __syncthreads();
  bf16_t* op = xnT + ((size_t)b * NPIX + p0) * CH + c0;
  #pragma unroll
  for (int j = 0; j < 4; ++j) {
    int p = ty + j * 8;
    op[(size_t)p * CH + tx] = (bf16_t)tile[tx][p];
  }
}

// ---------------- cast weights to bf16 ----------------
__global__ __launch_bounds__(256) void cast_w_k(const float* __restrict__ wq,
    const float* __restrict__ wp, bf16_t* __restrict__ wqb, bf16_t* __restrict__ wpb) {
  int i = blockIdx.x * 256 + threadIdx.x;
  if (i < 768 * 256) wqb[i] = (bf16_t)wq[i];
  if (i < 256 * 256) wpb[i] = (bf16_t)wp[i];
}

// ---------------- NT GEMM (modes 0,3) ----------------
#define LSTR 80

template <int MODE>
__global__ __launch_bounds__(256) void gemm_nt_k(
    const bf16_t* __restrict__ Ag, const bf16_t* __restrict__ Bg,
    int lda, int ldb, int K,
    void* __restrict__ O0, void* __restrict__ O1,
    const float* __restrict__ bias, const float* __restrict__ resid) {
  __shared__ __align__(16) char ldsA[128 * LSTR];
  __shared__ __align__(16) char ldsB[128 * LSTR];

  const int t = threadIdx.x;
  const int l = t & 63;
  const int w = t >> 6;
  const int wr = w >> 1, wc = w & 1;
  const int bm = blockIdx.x * 128;
  const int bn = blockIdx.y * 128;
  const int bz = blockIdx.z;

  const bf16_t* Ap = Ag;
  const bf16_t* Bp = Bg;
  if constexpr (MODE == 0) Ap += (size_t)bz * NPIX * CH;
  if constexpr (MODE == 3) Bp += (size_t)bz * NPIX * CH;

  f32x4 acc[4][4] = {};

  const int srow = t >> 2;
  const int scol = (t & 3) * 8;

  for (int k0 = 0; k0 < K; k0 += 32) {
    __syncthreads();
    #pragma unroll
    for (int it = 0; it < 2; ++it) {
      int r = it * 64 + srow;
      *(bf16x8*)(ldsA + r * LSTR + scol * 2) =
          *(const bf16x8*)(Ap + (size_t)(bm + r) * lda + k0 + scol);
      *(bf16x8*)(ldsB + r * LSTR + scol * 2) =
          *(const bf16x8*)(Bp + (size_t)(bn + r) * ldb + k0 + scol);
    }
    __syncthreads();
    bf16x8 fa[4], fb[4];
    #pragma unroll
    for (int m = 0; m < 4; ++m)
      fa[m] = *(const bf16x8*)(ldsA + (wr * 64 + m * 16 + (l & 15)) * LSTR + (l >> 4) * 16);
    #pragma unroll
    for (int n = 0; n < 4; ++n)
      fb[n] = *(const bf16x8*)(ldsB + (wc * 64 + n * 16 + (l & 15)) * LSTR + (l >> 4) * 16);
    #pragma unroll
    for (int m = 0; m < 4; ++m)
      #pragma unroll
      for (int n = 0; n < 4; ++n)
        acc[m][n] = __builtin_amdgcn_mfma_f32_16x16x32_bf16(fa[m], fb[n], acc[m][n], 0, 0, 0);
  }

  const int r0 = bm + wr * 64 + (l >> 4) * 4;
  const int c0 = bn + wc * 64 + (l & 15);
  #pragma unroll
  for (int m = 0; m < 4; ++m) {
    #pragma unroll
    for (int n = 0; n < 4; ++n) {
      int col = c0 + n * 16;
      #pragma unroll
      for (int j = 0; j < 4; ++j) {
        int row = r0 + m * 16 + j;
        float v = acc[m][n][j];
        if constexpr (MODE == 0) {
          float val = v + bias[col];
          if (col < 512)
            ((bf16_t*)O0)[(size_t)bz * NPIX * 512 + (size_t)row * 512 + col] = (bf16_t)val;
          else
            ((bf16_t*)O1)[(size_t)bz * CH * NPIX + (size_t)(col - 512) * NPIX + row] = (bf16_t)val;
        } else {
          size_t idx = (size_t)bz * CH * NPIX + (size_t)row * NPIX + col;
          ((float*)O0)[idx] = v + bias[row] + resid[idx];
        }
      }
    }
  }
}

// ---------------- fused flash attention ----------------
// 256 threads = 4 waves, each wave owns 32 q rows (Q-tile 128). KVBLK=128.
// Swapped QK^T: S^T = mfma(A=K, B=Q) -> lane owns one q col (l&31); m/lsum scalar.
// P redistributed to PV A-frags in-register (pack + shfl_xor 32).
#define KSTRIDE 528   // 512B row + 16 pad (2-way-free banks)
#define VSTRIDE 272   // 256B row + 16 pad

__device__ inline unsigned int pack2bf(float lo, float hi) {
  unsigned short a = __builtin_bit_cast(unsigned short, (bf16_t)lo);
  unsigned short b = __builtin_bit_cast(unsigned short, (bf16_t)hi);
  return (unsigned int)a | ((unsigned int)b << 16);
}

__global__ __launch_bounds__(256, 1) void flash_k(
    const bf16_t* __restrict__ qkT, const bf16_t* __restrict__ vbuf,
    bf16_t* __restrict__ OT) {
  __shared__ __align__(16) char kbuf[128 * KSTRIDE];   // 67.5 KB
  __shared__ __align__(16) char vlds[256 * VSTRIDE];   // 68   KB

  const int t = threadIdx.x;
  const int l = t & 63, w = t >> 6;
  const int lq = l & 31;          // this lane's q (within wave tile)
  const int h  = l >> 5;          // half-wave
  const int batch = blockIdx.x & 7;        // XCD-affine: one batch per XCD
  const int q0 = (blockIdx.x >> 3) * 128;

  const bf16_t* qk_b = qkT + (size_t)batch * NPIX * 512;
  const bf16_t* v_b  = vbuf + (size_t)batch * CH * NPIX;

  // Q fragments (stay in regs): lane holds Q[q0+w*32+lq][kk*16 + h*8 +: 8]
  bf16x8 qf[16];
  #pragma unroll
  for (int kk = 0; kk < 16; ++kk)
    qf[kk] = *(const bf16x8*)(qk_b + (size_t)(q0 + w * 32 + lq) * 512 + kk * 16 + h * 8);

  // prefetch K tile 0 into regs
  bf16x8 kreg[16];
  #pragma unroll
  for (int it = 0; it < 16; ++it)
    kreg[it] = *(const bf16x8*)(qk_b + (size_t)(it * 8 + (t >> 5)) * 512 + 256 + (t & 31) * 8);

  f32x16 acc_o[8] = {};
  float m = -1e30f, lsum = 0.f;
  const float c1 = 0.09016844006f;  // log2(e)/sqrt(256)

  for (int tile = 0; tile < 32; ++tile) {
    const int kv0 = tile * 128;
    // stage K
    #pragma unroll
    for (int it = 0; it < 16; ++it)
      *(bf16x8*)(kbuf + (it * 8 + (t >> 5)) * KSTRIDE + (t & 31) * 16) = kreg[it];
    __syncthreads();

    // issue V loads early (land during QK^T)
    bf16x8 vreg[16];
    #pragma unroll
    for (int it = 0; it < 16; ++it)
      vreg[it] = *(const bf16x8*)(v_b + (size_t)(it * 16 + (t >> 4)) * NPIX + kv0 + (t & 15) * 8);

    // QK^T (swapped): s[n] = S^T tile rows kv=n*32.., col q=lq
    f32x16 s[4] = {};
    #pragma unroll
    for (int kk = 0; kk < 16; ++kk) {
      #pragma unroll
      for (int n = 0; n < 4; ++n) {
        bf16x8 kf = *(const bf16x8*)(kbuf + (n * 32 + lq) * KSTRIDE + kk * 32 + h * 16);
        s[n] = __builtin_amdgcn_mfma_f32_32x32x16_bf16(kf, qf[kk], s[n], 0, 0, 0);
      }
    }

    // online softmax (per-lane scalar state; lane covers 64 of 128 kv, partner the rest)
    float tmax = -1e30f;
    #pragma unroll
    for (int n = 0; n < 4; ++n)
      #pragma unroll
      for (int r = 0; r < 16; ++r) {
        s[n][r] *= c1;
        tmax = fmaxf(tmax, s[n][r]);
      }
    tmax = fmaxf(tmax, __shfl_xor(tmax, 32, 64));
    float mnew = fmaxf(m, tmax);
    float sc = exp2f(m - mnew);
    m = mnew;
    float ls = 0.f;
    #pragma unroll
    for (int n = 0; n < 4; ++n)
      #pragma unroll
      for (int r = 0; r < 16; ++r) {
        float pv = exp2f(s[n][r] - mnew);
        s[n][r] = pv;
        ls += pv;
      }
    ls += __shfl_xor(ls, 32, 64);
    lsum = lsum * sc + ls;
    #pragma unroll
    for (int n2 = 0; n2 < 8; ++n2)
      #pragma unroll
      for (int r = 0; r < 16; ++r)
        acc_o[n2][r] *= sc;

    // build PV A-frags: pa[kk2] lane holds P[q=lq][kv = kk2*16 + h*8 +: 8]
    bf16x8 pa[8];
    #pragma unroll
    for (int kk2 = 0; kk2 < 8; ++kk2) {
      const int n = kk2 >> 1, hi = (kk2 & 1) * 8;
      unsigned int wkeep[2], wsend[2];
      #pragma unroll
      for (int j = 0; j < 2; ++j) {
        float a0 = s[n][2 * j + hi],     b0 = s[n][2 * j + 1 + hi];      // tgt h=0
        float a1 = s[n][2 * j + 4 + hi], b1 = s[n][2 * j + 5 + hi];      // tgt h=1
        float ka = h ? a1 : a0, kb = h ? b1 : b0;
        float sa = h ? a0 : a1, sb = h ? b0 : b1;
        wkeep[j] = pack2bf(ka, kb);
        wsend[j] = pack2bf(sa, sb);
      }
      unsigned int wr0 = __shfl_xor(wsend[0], 32, 64);
      unsigned int wr1 = __shfl_xor(wsend[1], 32, 64);
      unsigned int w0 = h ? wr0 : wkeep[0];
      unsigned int w1 = h ? wr1 : wkeep[1];
      unsigned int w2 = h ? wkeep[0] : wr0;
      unsigned int w3 = h ? wkeep[1] : wr1;
      union { unsigned int u[4]; bf16x8 v; } pu;
      pu.u[0] = w0; pu.u[1] = w1; pu.u[2] = w2; pu.u[3] = w3;
      pa[kk2] = pu.v;
    }

    // stage V (loads have landed under QK^T)
    #pragma unroll
    for (int it = 0; it < 16; ++it)
      *(bf16x8*)(vlds + (it * 16 + (t >> 4)) * VSTRIDE + (t & 15) * 16) = vreg[it];
    __syncthreads();

    // prefetch next K while PV runs
    if (tile < 31) {
      #pragma unroll
      for (int it = 0; it < 16; ++it)
        kreg[it] = *(const bf16x8*)(qk_b + (size_t)(kv0 + 128 + it * 8 + (t >> 5)) * 512 + 256 + (t & 31) * 8);
    }

    // PV: acc_o[n2] += P x V^T-frag
    #pragma unroll
    for (int kk2 = 0; kk2 < 8; ++kk2) {
      #pragma unroll
      for (int n2 = 0; n2 < 8; ++n2) {
        bf16x8 vf = *(const bf16x8*)(vlds + (n2 * 32 + lq) * VSTRIDE + kk2 * 32 + h * 16);
        acc_o[n2] = __builtin_amdgcn_mfma_f32_32x32x16_bf16(pa[kk2], vf, acc_o[n2], 0, 0, 0);
      }
    }
    __syncthreads();
  }

  // epilogue: O[q][c] / lsum -> OT [b][p][c] bf16
  float inv = 1.f / lsum;
  #pragma unroll
  for (int r = 0; r < 16; ++r) {
    const int row = (r & 3) + 8 * (r >> 2) + 4 * h;
    float iv = __shfl(inv, row, 64);
    bf16_t* orow = OT + (size_t)batch * NPIX * CH + (size_t)(q0 + w * 32 + row) * CH + lq;
    #pragma unroll
    for (int n2 = 0; n2 < 8; ++n2)
      orow[n2 * 32] = (bf16_t)(acc_o[n2][r] * iv);
  }
}

extern "C" void kernel_launch(void* const* d_in, const int* in_sizes, int n_in,
                              void* d_out, int out_size, void* d_ws, size_t ws_size,
                              hipStream_t stream) {
  const float* x      = (const float*)d_in[0];
  const float* gamma  = (const float*)d_in[1];
  const float* beta   = (const float*)d_in[2];
  const float* w_qkv  = (const float*)d_in[3];
  const float* b_qkv  = (const float*)d_in[4];
  const float* w_proj = (const float*)d_in[5];
  const float* b_proj = (const float*)d_in[6];

  char* p = (char*)d_ws;
  auto alloc = [&](size_t bytes) {
    char* r = p;
    p += (bytes + 255) & ~(size_t)255;
    return (void*)r;
  };
  bf16_t* qkT  = (bf16_t*)alloc((size_t)8 * NPIX * 512 * 2);  // 32MB  [b][p][q|k]
  bf16_t* vbuf = (bf16_t*)alloc((size_t)8 * CH * NPIX * 2);   // 16MB  [b][c][p]
  bf16_t* OT   = (bf16_t*)alloc((size_t)8 * NPIX * CH * 2);   // 16MB  [b][p][c]
  bf16_t* wqb  = (bf16_t*)alloc(768 * 256 * 2);
  bf16_t* wpb  = (bf16_t*)alloc(256 * 256 * 2);
  float*  acc2 = (float*)alloc(64 * 2 * 4);
  float*  stats= (float*)alloc(64 * 2 * 4);
  bf16_t* xnT  = (bf16_t*)d_out;  // scratch: dead before final proj writes d_out

  hipMemsetAsync(acc2, 0, 64 * 2 * 4, stream);
  gn_partial_k<<<64 * 8, 256, 0, stream>>>(x, acc2);
  gn_finalize_k<<<1, 64, 0, stream>>>(acc2, stats);
  gn_apply_t_k<<<dim3(128, 8, 8), dim3(32, 8), 0, stream>>>(x, stats, gamma, beta, xnT);
  cast_w_k<<<768, 256, 0, stream>>>(w_qkv, w_proj, wqb, wpb);

  // QKV: [p][o] = xnT[p][c] . w_qkv[o][c]
  gemm_nt_k<0><<<dim3(32, 6, 8), 256, 0, stream>>>(xnT, wqb, CH, CH, CH,
                                                   qkT, vbuf, b_qkv, nullptr);
  // fused attention (all batches)
  flash_k<<<256, 256, 0, stream>>>(qkT, vbuf, OT);

  // proj + bias + residual
  gemm_nt_k<3><<<dim3(2, 32, 8), 256, 0, stream>>>(wpb, OT, CH, CH, CH,
                                                   d_out, nullptr, b_proj, x);
}

// Round 4
// 353.045 us; speedup vs baseline: 2.0556x; 1.2665x over previous
//
#include <hip/hip_runtime.h>
#include <hip/hip_bf16.h>
#include <stdint.h>

typedef __bf16 bf16_t;
typedef __bf16 bf16x8 __attribute__((ext_vector_type(8)));
typedef __bf16 bf16x4 __attribute__((ext_vector_type(4)));
typedef float f32x4 __attribute__((ext_vector_type(4)));
typedef float f32x16 __attribute__((ext_vector_type(16)));

#define NPIX 4096
#define CH 256

// ---------------- GroupNorm stats (2-stage) ----------------
__global__ __launch_bounds__(256) void gn_partial_k(const float* __restrict__ x,
                                                    float* __restrict__ acc2) {
  int bg = blockIdx.x >> 3;
  int chunk = blockIdx.x & 7;
  const float4* xp = (const float4*)(x + (size_t)bg * 32 * NPIX) + chunk * (32 * NPIX / 4 / 8);
  float s = 0.f, ss = 0.f;
  for (int i = threadIdx.x; i < 32 * NPIX / 4 / 8; i += 256) {
    float4 v = xp[i];
    s  += v.x + v.y + v.z + v.w;
    ss += v.x * v.x + v.y * v.y + v.z * v.z + v.w * v.w;
  }
  int l = threadIdx.x & 63, w = threadIdx.x >> 6;
  #pragma unroll
  for (int off = 32; off; off >>= 1) { s += __shfl_down(s, off); ss += __shfl_down(ss, off); }
  __shared__ float rs[4], rss[4];
  if (l == 0) { rs[w] = s; rss[w] = ss; }
  __syncthreads();
  if (threadIdx.x == 0) {
    atomicAdd(&acc2[bg * 2],     rs[0] + rs[1] + rs[2] + rs[3]);
    atomicAdd(&acc2[bg * 2 + 1], rss[0] + rss[1] + rss[2] + rss[3]);
  }
}

__global__ void gn_finalize_k(const float* __restrict__ acc2, float* __restrict__ stats) {
  int bg = threadIdx.x;  // 64 threads
  float mean = acc2[bg * 2] * (1.f / (32.f * NPIX));
  float var  = acc2[bg * 2 + 1] * (1.f / (32.f * NPIX)) - mean * mean;
  stats[bg * 2]     = mean;
  stats[bg * 2 + 1] = rsqrtf(var + 1e-5f);
}

// ------------- normalize + transpose [b][c][p] -> bf16 [b][p][c] -------------
__global__ __launch_bounds__(256) void gn_apply_t_k(const float* __restrict__ x,
    const float* __restrict__ stats, const float* __restrict__ gamma,
    const float* __restrict__ beta, bf16_t* __restrict__ xnT) {
  __shared__ float tile[32][33];
  int b = blockIdx.z;
  int p0 = blockIdx.x * 32, c0 = blockIdx.y * 32;
  int g = c0 >> 5;
  float mean = stats[(b * 8 + g) * 2], rstd = stats[(b * 8 + g) * 2 + 1];
  int tx = threadIdx.x, ty = threadIdx.y;
  const float* xb = x + ((size_t)b * CH + c0) * NPIX + p0;
  #pragma unroll
  for (int j = 0; j < 4; ++j) {
    int c = ty + j * 8;
    float v = xb[(size_t)c * NPIX + tx];
    tile[c][tx] = (v - mean) * rstd * gamma[c0 + c] + beta[c0 + c];
  }
  __syncthreads();
  bf16_t* op = xnT + ((size_t)b * NPIX + p0) * CH + c0;
  #pragma unroll
  for (int j = 0; j < 4; ++j) {
    int p = ty + j * 8;
    op[(size_t)p * CH + tx] = (bf16_t)tile[tx][p];
  }
}

// ---------------- cast weights to bf16 ----------------
__global__ __launch_bounds__(256) void cast_w_k(const float* __restrict__ wq,
    const float* __restrict__ wp, bf16_t* __restrict__ wqb, bf16_t* __restrict__ wpb) {
  int i = blockIdx.x * 256 + threadIdx.x;
  if (i < 768 * 256) wqb[i] = (bf16_t)wq[i];
  if (i < 256 * 256) wpb[i] = (bf16_t)wp[i];
}

// ---------------- NT GEMM (modes 0,3) ----------------
#define LSTR 80

template <int MODE>
__global__ __launch_bounds__(256) void gemm_nt_k(
    const bf16_t* __restrict__ Ag, const bf16_t* __restrict__ Bg,
    int lda, int ldb, int K,
    void* __restrict__ O0, void* __restrict__ O1,
    const float* __restrict__ bias, const float* __restrict__ resid) {
  __shared__ __align__(16) char ldsA[128 * LSTR];
  __shared__ __align__(16) char ldsB[128 * LSTR];

  const int t = threadIdx.x;
  const int l = t & 63;
  const int w = t >> 6;
  const int wr = w >> 1, wc = w & 1;
  const int bm = blockIdx.x * 128;
  const int bn = blockIdx.y * 128;
  const int bz = blockIdx.z;

  const bf16_t* Ap = Ag;
  const bf16_t* Bp = Bg;
  if constexpr (MODE == 0) Ap += (size_t)bz * NPIX * CH;
  if constexpr (MODE == 3) Bp += (size_t)bz * NPIX * CH;

  f32x4 acc[4][4] = {};

  const int srow = t >> 2;
  const int scol = (t & 3) * 8;

  for (int k0 = 0; k0 < K; k0 += 32) {
    __syncthreads();
    #pragma unroll
    for (int it = 0; it < 2; ++it) {
      int r = it * 64 + srow;
      *(bf16x8*)(ldsA + r * LSTR + scol * 2) =
          *(const bf16x8*)(Ap + (size_t)(bm + r) * lda + k0 + scol);
      *(bf16x8*)(ldsB + r * LSTR + scol * 2) =
          *(const bf16x8*)(Bp + (size_t)(bn + r) * ldb + k0 + scol);
    }
    __syncthreads();
    bf16x8 fa[4], fb[4];
    #pragma unroll
    for (int m = 0; m < 4; ++m)
      fa[m] = *(const bf16x8*)(ldsA + (wr * 64 + m * 16 + (l & 15)) * LSTR + (l >> 4) * 16);
    #pragma unroll
    for (int n = 0; n < 4; ++n)
      fb[n] = *(const bf16x8*)(ldsB + (wc * 64 + n * 16 + (l & 15)) * LSTR + (l >> 4) * 16);
    #pragma unroll
    for (int m = 0; m < 4; ++m)
      #pragma unroll
      for (int n = 0; n < 4; ++n)
        acc[m][n] = __builtin_amdgcn_mfma_f32_16x16x32_bf16(fa[m], fb[n], acc[m][n], 0, 0, 0);
  }

  const int r0 = bm + wr * 64 + (l >> 4) * 4;
  const int c0 = bn + wc * 64 + (l & 15);
  #pragma unroll
  for (int m = 0; m < 4; ++m) {
    #pragma unroll
    for (int n = 0; n < 4; ++n) {
      int col = c0 + n * 16;
      #pragma unroll
      for (int j = 0; j < 4; ++j) {
        int row = r0 + m * 16 + j;
        float v = acc[m][n][j];
        if constexpr (MODE == 0) {
          float val = v + bias[col];
          if (col < 512)
            ((bf16_t*)O0)[(size_t)bz * NPIX * 512 + (size_t)row * 512 + col] = (bf16_t)val;
          else
            ((bf16_t*)O1)[(size_t)bz * CH * NPIX + (size_t)(col - 512) * NPIX + row] = (bf16_t)val;
        } else {
          size_t idx = (size_t)bz * CH * NPIX + (size_t)row * NPIX + col;
          ((float*)O0)[idx] = v + bias[row] + resid[idx];
        }
      }
    }
  }
}

// ---------------- fused flash attention ----------------
// 512 threads = 8 waves. Q-tile 128 = 4 q-groups x 32; wave (g,half) handles
// q-group g, kv-half `half` of each KVBLK=64 tile; independent online softmax
// per wave, merged pairwise at the end via LDS.
// K,V double-buffered in LDS via global_load_lds (linear dest) with
// XOR-swizzled SOURCE addresses; ds_reads apply the same XOR (G21).
#define KVB 64
#define KBYTES 32768   // 64 kv rows * 512 B (256 ch bf16)
#define VBYTES 32768   // 256 c rows * 128 B (64 kv bf16)

__device__ __forceinline__ void dma16(const void* g, void* l) {
  __builtin_amdgcn_global_load_lds(
      (const __attribute__((address_space(1))) unsigned int*)g,
      (__attribute__((address_space(3))) unsigned int*)l, 16, 0, 0);
}

__device__ inline unsigned int pack2bf(float lo, float hi) {
  unsigned short a = __builtin_bit_cast(unsigned short, (bf16_t)lo);
  unsigned short b = __builtin_bit_cast(unsigned short, (bf16_t)hi);
  return (unsigned int)a | ((unsigned int)b << 16);
}

__global__ __launch_bounds__(512, 2) void flash_k(
    const bf16_t* __restrict__ qkT, const bf16_t* __restrict__ vglob,
    bf16_t* __restrict__ OT) {
  __shared__ __align__(16) char kS[2 * KBYTES];
  __shared__ __align__(16) char vS[2 * VBYTES];
  __shared__ float mls[8][2][32];

  const int t = threadIdx.x;
  const int l = t & 63, w = t >> 6;       // w 0..7
  const int lq = l & 31, h = l >> 5;
  const int g = w >> 1, half = w & 1;
  const int batch = blockIdx.x & 7;        // one batch per XCD
  const int q0 = (blockIdx.x >> 3) * 128;

  const bf16_t* qk_b = qkT + (size_t)batch * NPIX * 512;
  const bf16_t* v_b  = vglob + (size_t)batch * CH * NPIX;

  // Q fragments (persistent): lane holds Q[q0+g*32+lq][kk*16 + h*8 +: 8]
  bf16x8 qf[16];
  const bf16_t* qrow = qk_b + (size_t)(q0 + g * 32 + lq) * 512 + h * 8;
  #pragma unroll
  for (int kk = 0; kk < 16; ++kk) qf[kk] = *(const bf16x8*)(qrow + kk * 16);

  // DMA lane geometry (wave-uniform LDS base + lane*16 linear dest)
  const int krow_l = w * 8 + (l >> 5);   // + it*2
  const int kslot  = l & 31;
  const int vrow_l = w * 32 + (l >> 3);  // + it*8
  const int vslot  = l & 7;
  const bf16_t* ksrc = qk_b + 256;

  auto stage = [&](int tile, int buf) {
    #pragma unroll
    for (int it = 0; it < 4; ++it) {
      int r = krow_l + it * 2;
      dma16(ksrc + (size_t)(tile * KVB + r) * 512 + ((kslot ^ (r & 31)) << 3),
            kS + buf * KBYTES + (w * 8 + it * 2) * 512);
      int c = vrow_l + it * 8;
      dma16(v_b + (size_t)c * NPIX + tile * KVB + ((vslot ^ (c & 7)) << 3),
            vS + buf * VBYTES + (w * 32 + it * 8) * 128);
    }
  };

  stage(0, 0);
  __syncthreads();

  f32x16 acc_o[8] = {};
  float m = -1e30f, lsum = 0.f;
  const float c1 = 0.09016844006f;  // log2(e)/sqrt(256)
  const int krow = half * 32 + lq;

  for (int tile = 0; tile < 64; ++tile) {
    const int cur = tile & 1;
    if (tile < 63) stage(tile + 1, cur ^ 1);

    // QK^T (swapped): s = S^T[kv = half*32 + crow(r,h)][q = lq]
    f32x16 s = {};
    const char* kbase = kS + cur * KBYTES + krow * 512;
    #pragma unroll
    for (int kk = 0; kk < 16; ++kk) {
      bf16x8 kf = *(const bf16x8*)(kbase + (((2 * kk + h) ^ lq) << 4));
      s = __builtin_amdgcn_mfma_f32_32x32x16_bf16(kf, qf[kk], s, 0, 0, 0);
    }

    // online softmax, log2 domain, defer-max (T13)
    float tmax = -1e30f;
    #pragma unroll
    for (int r = 0; r < 16; ++r) { s[r] *= c1; tmax = fmaxf(tmax, s[r]); }
    tmax = fmaxf(tmax, __shfl_xor(tmax, 32, 64));
    if (!__all(tmax <= m + 10.f)) {
      float mnew = fmaxf(m, tmax);
      float sc = exp2f(m - mnew);
      m = mnew; lsum *= sc;
      #pragma unroll
      for (int n2 = 0; n2 < 8; ++n2)
        #pragma unroll
        for (int r = 0; r < 16; ++r) acc_o[n2][r] *= sc;
    }
    float ls = 0.f;
    #pragma unroll
    for (int r = 0; r < 16; ++r) { float p = exp2f(s[r] - m); s[r] = p; ls += p; }
    ls += __shfl_xor(ls, 32, 64);
    lsum += ls;

    // pack P -> PV A-frags: pa[kk2] = P[q=lq][kv_local = kk2*16 + h*8 +: 8]
    bf16x8 pa[2];
    #pragma unroll
    for (int kk2 = 0; kk2 < 2; ++kk2) {
      const int hi = kk2 * 8;
      unsigned int wkeep[2], wsend[2];
      #pragma unroll
      for (int j = 0; j < 2; ++j) {
        float a0 = s[2 * j + hi],     b0 = s[2 * j + 1 + hi];
        float a1 = s[2 * j + 4 + hi], b1 = s[2 * j + 5 + hi];
        float ka = h ? a1 : a0, kb = h ? b1 : b0;
        float sa = h ? a0 : a1, sb = h ? b0 : b1;
        wkeep[j] = pack2bf(ka, kb);
        wsend[j] = pack2bf(sa, sb);
      }
      unsigned int wr0 = __shfl_xor(wsend[0], 32, 64);
      unsigned int wr1 = __shfl_xor(wsend[1], 32, 64);
      union { unsigned int u[4]; bf16x8 v; } pu;
      pu.u[0] = h ? wr0 : wkeep[0];
      pu.u[1] = h ? wr1 : wkeep[1];
      pu.u[2] = h ? wkeep[0] : wr0;
      pu.u[3] = h ? wkeep[1] : wr1;
      pa[kk2] = pu.v;
    }

    // PV: acc_o[n2] += P x V[c = n2*32+lq][kv half]
    const char* vbase = vS + cur * VBYTES;
    #pragma unroll
    for (int n2 = 0; n2 < 8; ++n2) {
      const int vr = n2 * 32 + lq;
      #pragma unroll
      for (int kk2 = 0; kk2 < 2; ++kk2) {
        bf16x8 vf = *(const bf16x8*)(vbase + vr * 128 +
                     (((4 * half + 2 * kk2 + h) ^ (lq & 7)) << 4));
        acc_o[n2] = __builtin_amdgcn_mfma_f32_32x32x16_bf16(pa[kk2], vf, acc_o[n2], 0, 0, 0);
      }
    }
    __syncthreads();
  }

  // ---- merge wave pairs (2g, 2g+1): complementary kv halves ----
  if (h == 0) { mls[w][0][lq] = m; mls[w][1][lq] = lsum; }
  char* abuf = (g < 2) ? (kS + g * 32768) : (vS + (g - 2) * 32768);
  if (half == 1) {
    float* ab = (float*)abuf + l * 128;
    #pragma unroll
    for (int n2 = 0; n2 < 8; ++n2)
      #pragma unroll
      for (int q4 = 0; q4 < 4; ++q4) {
        f32x4 vv;
        vv[0] = acc_o[n2][q4 * 4 + 0]; vv[1] = acc_o[n2][q4 * 4 + 1];
        vv[2] = acc_o[n2][q4 * 4 + 2]; vv[3] = acc_o[n2][q4 * 4 + 3];
        *(f32x4*)(ab + n2 * 16 + q4 * 4) = vv;
      }
  }
  __syncthreads();
  if (half == 0) {
    float mB = mls[w + 1][0][lq], lB = mls[w + 1][1][lq];
    float mS = fmaxf(m, mB);
    float sA = exp2f(m - mS), sB = exp2f(mB - mS);
    float inv = 1.f / (lsum * sA + lB * sB);
    const float* ab = (const float*)abuf + l * 128;
    bf16_t* obase = OT + (size_t)batch * NPIX * CH + (size_t)(q0 + g * 32) * CH + lq;
    #pragma unroll
    for (int r = 0; r < 16; ++r) {
      int q = (r & 3) + 8 * (r >> 2) + 4 * h;
      float sAr = __shfl(sA, q, 64);
      float sBr = __shfl(sB, q, 64);
      float ivr = __shfl(inv, q, 64);
      bf16_t* orow = obase + (size_t)q * CH;
      #pragma unroll
      for (int n2 = 0; n2 < 8; ++n2) {
        float ob = (acc_o[n2][r] * sAr + ab[n2 * 16 + r] * sBr) * ivr;
        orow[n2 * 32] = (bf16_t)ob;
      }
    }
  }
}

extern "C" void kernel_launch(void* const* d_in, const int* in_sizes, int n_in,
                              void* d_out, int out_size, void* d_ws, size_t ws_size,
                              hipStream_t stream) {
  const float* x      = (const float*)d_in[0];
  const float* gamma  = (const float*)d_in[1];
  const float* beta   = (const float*)d_in[2];
  const float* w_qkv  = (const float*)d_in[3];
  const float* b_qkv  = (const float*)d_in[4];
  const float* w_proj = (const float*)d_in[5];
  const float* b_proj = (const float*)d_in[6];

  char* p = (char*)d_ws;
  auto alloc = [&](size_t bytes) {
    char* r = p;
    p += (bytes + 255) & ~(size_t)255;
    return (void*)r;
  };
  bf16_t* qkT  = (bf16_t*)alloc((size_t)8 * NPIX * 512 * 2);  // 32MB  [b][p][q|k]
  bf16_t* vbuf = (bf16_t*)alloc((size_t)8 * CH * NPIX * 2);   // 16MB  [b][c][p]
  bf16_t* OT   = (bf16_t*)alloc((size_t)8 * NPIX * CH * 2);   // 16MB  [b][p][c]
  bf16_t* wqb  = (bf16_t*)alloc(768 * 256 * 2);
  bf16_t* wpb  = (bf16_t*)alloc(256 * 256 * 2);
  float*  acc2 = (float*)alloc(64 * 2 * 4);
  float*  stats= (float*)alloc(64 * 2 * 4);
  bf16_t* xnT  = (bf16_t*)d_out;  // scratch: dead before final proj writes d_out

  hipMemsetAsync(acc2, 0, 64 * 2 * 4, stream);
  gn_partial_k<<<64 * 8, 256, 0, stream>>>(x, acc2);
  gn_finalize_k<<<1, 64, 0, stream>>>(acc2, stats);
  gn_apply_t_k<<<dim3(128, 8, 8), dim3(32, 8), 0, stream>>>(x, stats, gamma, beta, xnT);
  cast_w_k<<<768, 256, 0, stream>>>(w_qkv, w_proj, wqb, wpb);

  // QKV: [p][o] = xnT[p][c] . w_qkv[o][c]
  gemm_nt_k<0><<<dim3(32, 6, 8), 256, 0, stream>>>(xnT, wqb, CH, CH, CH,
                                                   qkT, vbuf, b_qkv, nullptr);
  // fused attention (all batches): 256 blocks x 512 thr
  flash_k<<<256, 512, 0, stream>>>(qkT, vbuf, OT);

  // proj + bias + residual
  gemm_nt_k<3><<<dim3(2, 32, 8), 256, 0, stream>>>(wpb, OT, CH, CH, CH,
                                                   d_out, nullptr, b_proj, x);
}